// Round 5
// baseline (512.440 us; speedup 1.0000x reference)
//
#include <hip/hip_runtime.h>

#define NN 50000
#define NE 800000

// ---- degrees: 8-way striped int atomics (stripe = blockIdx&7) --------------
// str layout: [(2*s+0)*NN + n] = out-degree stripe s, [(2*s+1)*NN + n] = in.
__global__ void degree_striped_kernel(const int* __restrict__ src, const int* __restrict__ dst,
                                      int* __restrict__ str) {
    int e = blockIdx.x * 256 + threadIdx.x;
    if (e < NE) {
        int s = blockIdx.x & 7;
        atomicAdd(&str[(2 * s + 0) * NN + src[e]], 1);
        atomicAdd(&str[(2 * s + 1) * NN + dst[e]], 1);
    }
}

// fold stripes; emit din_cnt (for scan) + rsqrt normalizers (no aliasing)
__global__ void degree_reduce_kernel(const int* __restrict__ str, int* __restrict__ din_cnt,
                                     float* __restrict__ dout_is, float* __restrict__ din_is) {
    int n = blockIdx.x * 256 + threadIdx.x;
    if (n >= NN) return;
    int so = 0, si = 0;
#pragma unroll
    for (int s = 0; s < 8; ++s) {
        so += str[(2 * s + 0) * NN + n];
        si += str[(2 * s + 1) * NN + n];
    }
    din_cnt[n] = si;
    dout_is[n] = rsqrtf(fmaxf((float)so, 1.0f));
    din_is[n]  = rsqrtf(fmaxf((float)si, 1.0f));
}

// ---- scan helpers ----------------------------------------------------------
__device__ inline int wave_incl_scan(int v) {
    int lane = threadIdx.x & 63;
#pragma unroll
    for (int off = 1; off < 64; off <<= 1) {
        int t = __shfl_up(v, off, 64);
        if (lane >= off) v += t;
    }
    return v;
}

// A: per-block local exclusive scan of in-degree; block totals to partials
__global__ void scan_local_kernel(const int* __restrict__ din_cnt,
                                  int* __restrict__ row_start,
                                  int* __restrict__ partials) {
    __shared__ int wsum[4];
    int i = blockIdx.x * 256 + threadIdx.x;
    int v = (i < NN) ? din_cnt[i] : 0;
    int lane = threadIdx.x & 63, wid = threadIdx.x >> 6;
    int incl = wave_incl_scan(v);
    if (lane == 63) wsum[wid] = incl;
    __syncthreads();
    if (threadIdx.x == 0) {
        int s = 0;
        for (int w = 0; w < 4; ++w) { int t = wsum[w]; wsum[w] = s; s += t; }
        partials[blockIdx.x] = s;
    }
    __syncthreads();
    if (i < NN) row_start[i] = incl - v + wsum[wid];
}

// B: single-block exclusive scan of the 196 partials (in place)
__global__ void scan_partials_kernel(int* __restrict__ partials, int nparts,
                                     int* __restrict__ row_start) {
    __shared__ int wsum[4];
    int v = (threadIdx.x < nparts) ? partials[threadIdx.x] : 0;
    int lane = threadIdx.x & 63, wid = threadIdx.x >> 6;
    int incl = wave_incl_scan(v);
    if (lane == 63) wsum[wid] = incl;
    __syncthreads();
    if (threadIdx.x == 0) {
        int s = 0;
        for (int w = 0; w < 4; ++w) { int t = wsum[w]; wsum[w] = s; s += t; }
        row_start[NN] = NE;  // total in-degree == edge count
    }
    __syncthreads();
    if (threadIdx.x < nparts) partials[threadIdx.x] = incl - v + wsum[wid];
}

// C: add block offsets
__global__ void scan_add_kernel(int* __restrict__ row_start, const int* __restrict__ partials) {
    int i = blockIdx.x * 256 + threadIdx.x;
    if (i < NN) row_start[i] += partials[blockIdx.x];
}

// fill CSR: group src by dst
__global__ void csr_fill_kernel(const int* __restrict__ src, const int* __restrict__ dst,
                                const int* __restrict__ row_start, int* __restrict__ cursor,
                                int* __restrict__ csr_src) {
    int e = blockIdx.x * 256 + threadIdx.x;
    if (e < NE) {
        int d = dst[e];
        int pos = atomicAdd(&cursor[d], 1);
        csr_src[row_start[d] + pos] = src[e];
    }
}

// ---- X = rowscale(A) @ W, register-blocked 64x64 tile ----------------------
// Block: 256 threads -> 64 rows x 64 cols, 4x4 acc per thread.
// A staged TRANSPOSED in LDS (pitch 68); W staged row-major. Staged row index
// is CLAMPED to NN-1 (always-in-bounds loads); stores are guarded.
template <int K>
__global__ __launch_bounds__(256) void proj_kernel(
    const float* __restrict__ A, int lda,
    const float* __restrict__ W,   // K x 64, row-major
    const float* __restrict__ scale,
    float* __restrict__ X) {
    constexpr int KC = 64;
    constexpr int NCHUNK = K / KC;
    __shared__ float sAT[KC * 68];  // [k][row], pitch 68
    __shared__ float sW[KC * 64];   // [k][col]
    float acc[4][4] = {};

    const int t = threadIdx.x;
    const int tx = t & 15;          // col group: cols 4*tx..4*tx+3
    const int ty = t >> 4;          // row group: rows 4*ty..4*ty+3
    const int row0 = blockIdx.x * 64;

    const int srow = t & 63;        // staging: one row per lane
    const int f0 = t >> 6;          // staging float4-col base (0..3)
    int grow = row0 + srow;
    if (grow > NN - 1) grow = NN - 1;   // clamp: loads always in-bounds
    const float* arow = A + (size_t)grow * lda;

    for (int kc = 0; kc < NCHUNK; ++kc) {
        // stage A chunk transposed: sAT[k][srow] = A[grow][kc*64 + k]
#pragma unroll
        for (int it = 0; it < 4; ++it) {
            int k = (f0 + it * 4) * 4;
            float4 a4 = *reinterpret_cast<const float4*>(arow + kc * KC + k);
            sAT[(k + 0) * 68 + srow] = a4.x;
            sAT[(k + 1) * 68 + srow] = a4.y;
            sAT[(k + 2) * 68 + srow] = a4.z;
            sAT[(k + 3) * 68 + srow] = a4.w;
        }
        // stage W chunk coalesced (64x64 floats = 1024 float4)
        {
            const float4* wsrc = reinterpret_cast<const float4*>(W + (size_t)kc * KC * 64);
            float4* wdst = reinterpret_cast<float4*>(sW);
#pragma unroll
            for (int it = 0; it < 4; ++it) wdst[t + it * 256] = wsrc[t + it * 256];
        }
        __syncthreads();
#pragma unroll 8
        for (int k = 0; k < KC; ++k) {
            float4 av = *reinterpret_cast<const float4*>(&sAT[k * 68 + ty * 4]);
            float4 wv = *reinterpret_cast<const float4*>(&sW[k * 64 + tx * 4]);
            acc[0][0] = fmaf(av.x, wv.x, acc[0][0]);
            acc[0][1] = fmaf(av.x, wv.y, acc[0][1]);
            acc[0][2] = fmaf(av.x, wv.z, acc[0][2]);
            acc[0][3] = fmaf(av.x, wv.w, acc[0][3]);
            acc[1][0] = fmaf(av.y, wv.x, acc[1][0]);
            acc[1][1] = fmaf(av.y, wv.y, acc[1][1]);
            acc[1][2] = fmaf(av.y, wv.z, acc[1][2]);
            acc[1][3] = fmaf(av.y, wv.w, acc[1][3]);
            acc[2][0] = fmaf(av.z, wv.x, acc[2][0]);
            acc[2][1] = fmaf(av.z, wv.y, acc[2][1]);
            acc[2][2] = fmaf(av.z, wv.z, acc[2][2]);
            acc[2][3] = fmaf(av.z, wv.w, acc[2][3]);
            acc[3][0] = fmaf(av.w, wv.x, acc[3][0]);
            acc[3][1] = fmaf(av.w, wv.y, acc[3][1]);
            acc[3][2] = fmaf(av.w, wv.z, acc[3][2]);
            acc[3][3] = fmaf(av.w, wv.w, acc[3][3]);
        }
        __syncthreads();
    }
    // store: X[r, 4tx..4tx+3], row-scale applied here
#pragma unroll
    for (int i = 0; i < 4; ++i) {
        int r = row0 + ty * 4 + i;
        if (r < NN) {
            float s = scale ? scale[r] : 1.0f;
            float4 o = {acc[i][0] * s, acc[i][1] * s, acc[i][2] * s, acc[i][3] * s};
            *reinterpret_cast<float4*>(X + (size_t)r * 64 + tx * 4) = o;
        }
    }
}

// ---- pull-mode aggregation: one wave per dst node, lane = column -----------
// DOUBLE accumulators: result insensitive (to ~1e-13) to the per-row slot
// order produced by csr_fill's atomic cursor -> launch-to-launch stable.
// din_is != nullptr: out[n, coff+c] = relu(sum * din_is[n] + b[c])   (layer)
// din_is == nullptr: out[n, coff+c] = sum + b[c]                     (tail)
__global__ __launch_bounds__(256) void gather_kernel(
    const int* __restrict__ row_start, const int* __restrict__ csr_src,
    const float* __restrict__ X, const float* __restrict__ din_is,
    const float* __restrict__ b, float* __restrict__ out,
    int ldo, int coff) {
    int n = blockIdx.x * 4 + (threadIdx.x >> 6);
    int c = threadIdx.x & 63;
    if (n >= NN) return;
    int s0 = row_start[n], s1 = row_start[n + 1];
    double da = 0.0, db = 0.0;
    int i = s0;
    int n8 = s0 + ((s1 - s0) & ~7);
    for (; i < n8; i += 8) {
        int i0 = csr_src[i + 0], i1 = csr_src[i + 1], i2 = csr_src[i + 2], i3 = csr_src[i + 3];
        int i4 = csr_src[i + 4], i5 = csr_src[i + 5], i6 = csr_src[i + 6], i7 = csr_src[i + 7];
        float v0 = X[(size_t)i0 * 64 + c];
        float v1 = X[(size_t)i1 * 64 + c];
        float v2 = X[(size_t)i2 * 64 + c];
        float v3 = X[(size_t)i3 * 64 + c];
        float v4 = X[(size_t)i4 * 64 + c];
        float v5 = X[(size_t)i5 * 64 + c];
        float v6 = X[(size_t)i6 * 64 + c];
        float v7 = X[(size_t)i7 * 64 + c];
        da += (double)v0; db += (double)v1;
        da += (double)v2; db += (double)v3;
        da += (double)v4; db += (double)v5;
        da += (double)v6; db += (double)v7;
    }
    for (; i < s1; ++i) da += (double)X[(size_t)csr_src[i] * 64 + c];
    float acc = (float)(da + db);
    float* p = out + (size_t)n * ldo + coff + c;
    if (din_is) {
        *p = fmaxf(fmaf(acc, din_is[n], b[c]), 0.0f);
    } else {
        *p = acc + b[c];
    }
}

extern "C" void kernel_launch(void* const* d_in, const int* in_sizes, int n_in,
                              void* d_out, int out_size, void* d_ws, size_t ws_size,
                              hipStream_t stream) {
    const float* feat  = (const float*)d_in[0];
    const int*   src   = (const int*)d_in[1];
    const int*   dst   = (const int*)d_in[2];
    const float* W[4]  = {(const float*)d_in[3], (const float*)d_in[5],
                          (const float*)d_in[7], (const float*)d_in[9]};
    const float* b[4]  = {(const float*)d_in[4], (const float*)d_in[6],
                          (const float*)d_in[8], (const float*)d_in[10]};
    const float* W_mlp = (const float*)d_in[11];
    const float* b_mlp = (const float*)d_in[12];
    float* out = (float*)d_out;

    // workspace layout:
    // C [NN*256 f]  (head transiently reused: str [16*NN i] | cursor [NN i],
    //                both dead before gather-0 writes C)
    // X [NN*64 f] | dout_is [NN f] | din_is [NN f] | din_cnt [NN i] |
    // row_start [NN+1 i] | partials [256 i] | csr_src [NE i]
    float* C       = (float*)d_ws;
    int*   str     = (int*)d_ws;           // 16*NN ints (8 stripes x {out,in})
    int*   cursor  = str + 16 * NN;        // NN ints
    float* X       = C + (size_t)NN * 256;
    float* dout_is = X + (size_t)NN * 64;
    float* din_is  = dout_is + NN;
    int*   din_cnt   = (int*)(din_is + NN);
    int*   row_start = din_cnt + NN;
    int*   partials  = row_start + NN + 1;
    int*   csr_src   = partials + 256;

    const int NBLK = (NN + 255) / 256;   // 196
    const int GBLK = (NN + 63) / 64;     // 782 (GEMM tiles)

    // zero stripes + cursor in one shot (contiguous, 17*NN ints)
    hipMemsetAsync(str, 0, 17 * NN * sizeof(int), stream);

    degree_striped_kernel<<<(NE + 255) / 256, 256, 0, stream>>>(src, dst, str);
    degree_reduce_kernel<<<NBLK, 256, 0, stream>>>(str, din_cnt, dout_is, din_is);

    // CSR build
    scan_local_kernel<<<NBLK, 256, 0, stream>>>(din_cnt, row_start, partials);
    scan_partials_kernel<<<1, 256, 0, stream>>>(partials, NBLK, row_start);
    scan_add_kernel<<<NBLK, 256, 0, stream>>>(row_start, partials);
    csr_fill_kernel<<<(NE + 255) / 256, 256, 0, stream>>>(src, dst, row_start, cursor, csr_src);

    // layer 0 (K = 256 input feats)
    proj_kernel<256><<<GBLK, 256, 0, stream>>>(feat, 256, W[0], dout_is, X);
    gather_kernel<<<12500, 256, 0, stream>>>(row_start, csr_src, X, din_is, b[0], C, 256, 0);

    // layers 1..3 (K = 64), input = previous slice of C
    for (int i = 1; i < 4; ++i) {
        proj_kernel<64><<<GBLK, 256, 0, stream>>>(C + (i - 1) * 64, 256, W[i], dout_is, X);
        gather_kernel<<<12500, 256, 0, stream>>>(row_start, csr_src, X, din_is, b[i], C, 256, i * 64);
    }

    // tail: P = C @ W_mlp (project BEFORE the neighbor-sum; matmul is linear),
    // then out = b_mlp + segment_sum(P[src] -> dst)
    proj_kernel<256><<<GBLK, 256, 0, stream>>>(C, 256, W_mlp, nullptr, X);
    gather_kernel<<<12500, 256, 0, stream>>>(row_start, csr_src, X, nullptr, b_mlp, out, 64, 0);
}

// Round 6
// 466.795 us; speedup vs baseline: 1.0978x; 1.0978x over previous
//
#include <hip/hip_runtime.h>

#define NN 50000
#define NE 800000

// ---- bf16 helpers (manual RNE; values are finite) --------------------------
__device__ inline unsigned short f2bf(float f) {
    unsigned u = __float_as_uint(f);
    unsigned r = (u + 0x7FFFu + ((u >> 16) & 1u)) >> 16;
    return (unsigned short)r;
}
__device__ inline float bf2f(unsigned short h) {
    return __uint_as_float(((unsigned)h) << 16);
}

// ---- degree + CSR slot assignment in ONE atomic pass -----------------------
// dout_cnt[src]++ ; epos[e] = cursor[dst]++  (cursor doubles as din_cnt)
__global__ void degree_cursor_kernel(const int* __restrict__ src, const int* __restrict__ dst,
                                     int* __restrict__ dout_cnt, int* __restrict__ cursor,
                                     int* __restrict__ epos) {
    int e = blockIdx.x * 256 + threadIdx.x;
    if (e < NE) {
        atomicAdd(&dout_cnt[src[e]], 1);
        epos[e] = atomicAdd(&cursor[dst[e]], 1);
    }
}

// counts -> rsqrt normalizers (separate buffers, no aliasing)
__global__ void reduce_norm_kernel(const int* __restrict__ dout_cnt, const int* __restrict__ din_cnt,
                                   float* __restrict__ dout_is, float* __restrict__ din_is) {
    int n = blockIdx.x * 256 + threadIdx.x;
    if (n >= NN) return;
    dout_is[n] = rsqrtf(fmaxf((float)dout_cnt[n], 1.0f));
    din_is[n]  = rsqrtf(fmaxf((float)din_cnt[n], 1.0f));
}

// ---- scan helpers ----------------------------------------------------------
__device__ inline int wave_incl_scan(int v) {
    int lane = threadIdx.x & 63;
#pragma unroll
    for (int off = 1; off < 64; off <<= 1) {
        int t = __shfl_up(v, off, 64);
        if (lane >= off) v += t;
    }
    return v;
}

// A: per-block local exclusive scan of in-degree; block totals to partials
__global__ void scan_local_kernel(const int* __restrict__ din_cnt,
                                  int* __restrict__ row_start,
                                  int* __restrict__ partials) {
    __shared__ int wsum[4];
    int i = blockIdx.x * 256 + threadIdx.x;
    int v = (i < NN) ? din_cnt[i] : 0;
    int lane = threadIdx.x & 63, wid = threadIdx.x >> 6;
    int incl = wave_incl_scan(v);
    if (lane == 63) wsum[wid] = incl;
    __syncthreads();
    if (threadIdx.x == 0) {
        int s = 0;
        for (int w = 0; w < 4; ++w) { int t = wsum[w]; wsum[w] = s; s += t; }
        partials[blockIdx.x] = s;
    }
    __syncthreads();
    if (i < NN) row_start[i] = incl - v + wsum[wid];
}

// B: single-block exclusive scan of the 196 partials (in place)
__global__ void scan_partials_kernel(int* __restrict__ partials, int nparts,
                                     int* __restrict__ row_start) {
    __shared__ int wsum[4];
    int v = (threadIdx.x < nparts) ? partials[threadIdx.x] : 0;
    int lane = threadIdx.x & 63, wid = threadIdx.x >> 6;
    int incl = wave_incl_scan(v);
    if (lane == 63) wsum[wid] = incl;
    __syncthreads();
    if (threadIdx.x == 0) {
        int s = 0;
        for (int w = 0; w < 4; ++w) { int t = wsum[w]; wsum[w] = s; s += t; }
        row_start[NN] = NE;  // total in-degree == edge count
    }
    __syncthreads();
    if (threadIdx.x < nparts) partials[threadIdx.x] = incl - v + wsum[wid];
}

// C: add block offsets
__global__ void scan_add_kernel(int* __restrict__ row_start, const int* __restrict__ partials) {
    int i = blockIdx.x * 256 + threadIdx.x;
    if (i < NN) row_start[i] += partials[blockIdx.x];
}

// fill CSR: atomic-free scattered write using precomputed slots
__global__ void csr_fill_kernel(const int* __restrict__ src, const int* __restrict__ dst,
                                const int* __restrict__ row_start, const int* __restrict__ epos,
                                int* __restrict__ csr_src) {
    int e = blockIdx.x * 256 + threadIdx.x;
    if (e < NE) csr_src[row_start[dst[e]] + epos[e]] = src[e];
}

// ---- X = rowscale(A) @ W, register-blocked 64x64 tile ----------------------
// Block: 256 threads -> 64 rows x 64 cols, 4x4 acc per thread.
// A staged TRANSPOSED in LDS (pitch 68); W staged row-major. Staged row index
// CLAMPED to NN-1 (always-in-bounds loads); stores guarded.
// OUT_BF16: store X as bf16 (halves gather traffic); else f32.
template <int K, bool OUT_BF16>
__global__ __launch_bounds__(256) void proj_kernel(
    const float* __restrict__ A, int lda,
    const float* __restrict__ W,   // K x 64, row-major
    const float* __restrict__ scale,
    void* __restrict__ Xout) {
    constexpr int KC = 64;
    constexpr int NCHUNK = K / KC;
    __shared__ float sAT[KC * 68];  // [k][row], pitch 68
    __shared__ float sW[KC * 64];   // [k][col]
    float acc[4][4] = {};

    const int t = threadIdx.x;
    const int tx = t & 15;          // col group: cols 4*tx..4*tx+3
    const int ty = t >> 4;          // row group: rows 4*ty..4*ty+3
    const int row0 = blockIdx.x * 64;

    const int srow = t & 63;        // staging: one row per lane
    const int f0 = t >> 6;          // staging float4-col base (0..3)
    int grow = row0 + srow;
    if (grow > NN - 1) grow = NN - 1;   // clamp: loads always in-bounds
    const float* arow = A + (size_t)grow * lda;

    for (int kc = 0; kc < NCHUNK; ++kc) {
#pragma unroll
        for (int it = 0; it < 4; ++it) {
            int k = (f0 + it * 4) * 4;
            float4 a4 = *reinterpret_cast<const float4*>(arow + kc * KC + k);
            sAT[(k + 0) * 68 + srow] = a4.x;
            sAT[(k + 1) * 68 + srow] = a4.y;
            sAT[(k + 2) * 68 + srow] = a4.z;
            sAT[(k + 3) * 68 + srow] = a4.w;
        }
        {
            const float4* wsrc = reinterpret_cast<const float4*>(W + (size_t)kc * KC * 64);
            float4* wdst = reinterpret_cast<float4*>(sW);
#pragma unroll
            for (int it = 0; it < 4; ++it) wdst[t + it * 256] = wsrc[t + it * 256];
        }
        __syncthreads();
#pragma unroll 8
        for (int k = 0; k < KC; ++k) {
            float4 av = *reinterpret_cast<const float4*>(&sAT[k * 68 + ty * 4]);
            float4 wv = *reinterpret_cast<const float4*>(&sW[k * 64 + tx * 4]);
            acc[0][0] = fmaf(av.x, wv.x, acc[0][0]);
            acc[0][1] = fmaf(av.x, wv.y, acc[0][1]);
            acc[0][2] = fmaf(av.x, wv.z, acc[0][2]);
            acc[0][3] = fmaf(av.x, wv.w, acc[0][3]);
            acc[1][0] = fmaf(av.y, wv.x, acc[1][0]);
            acc[1][1] = fmaf(av.y, wv.y, acc[1][1]);
            acc[1][2] = fmaf(av.y, wv.z, acc[1][2]);
            acc[1][3] = fmaf(av.y, wv.w, acc[1][3]);
            acc[2][0] = fmaf(av.z, wv.x, acc[2][0]);
            acc[2][1] = fmaf(av.z, wv.y, acc[2][1]);
            acc[2][2] = fmaf(av.z, wv.z, acc[2][2]);
            acc[2][3] = fmaf(av.z, wv.w, acc[2][3]);
            acc[3][0] = fmaf(av.w, wv.x, acc[3][0]);
            acc[3][1] = fmaf(av.w, wv.y, acc[3][1]);
            acc[3][2] = fmaf(av.w, wv.z, acc[3][2]);
            acc[3][3] = fmaf(av.w, wv.w, acc[3][3]);
        }
        __syncthreads();
    }
#pragma unroll
    for (int i = 0; i < 4; ++i) {
        int r = row0 + ty * 4 + i;
        if (r < NN) {
            float s = scale ? scale[r] : 1.0f;
            float4 o = {acc[i][0] * s, acc[i][1] * s, acc[i][2] * s, acc[i][3] * s};
            if (OUT_BF16) {
                ushort4 h = {f2bf(o.x), f2bf(o.y), f2bf(o.z), f2bf(o.w)};
                *reinterpret_cast<ushort4*>((unsigned short*)Xout + (size_t)r * 64 + tx * 4) = h;
            } else {
                *reinterpret_cast<float4*>((float*)Xout + (size_t)r * 64 + tx * 4) = o;
            }
        }
    }
}

// ---- pull aggregation, bf16 rows: one wave per dst node, lane = column -----
// DOUBLE accumulators: order-insensitive -> launch-to-launch stable.
// out[n, coff+c] = relu(sum * din_is[n] + b[c])
__global__ __launch_bounds__(256) void gather_bf16_kernel(
    const int* __restrict__ row_start, const int* __restrict__ csr_src,
    const unsigned short* __restrict__ Xh, const float* __restrict__ din_is,
    const float* __restrict__ b, float* __restrict__ out,
    int ldo, int coff) {
    int n = blockIdx.x * 4 + (threadIdx.x >> 6);
    int c = threadIdx.x & 63;
    if (n >= NN) return;
    int s0 = row_start[n], s1 = row_start[n + 1];
    double da = 0.0, db = 0.0;
    int i = s0;
    int n8 = s0 + ((s1 - s0) & ~7);
    for (; i < n8; i += 8) {
        int i0 = csr_src[i + 0], i1 = csr_src[i + 1], i2 = csr_src[i + 2], i3 = csr_src[i + 3];
        int i4 = csr_src[i + 4], i5 = csr_src[i + 5], i6 = csr_src[i + 6], i7 = csr_src[i + 7];
        float v0 = bf2f(Xh[(size_t)i0 * 64 + c]);
        float v1 = bf2f(Xh[(size_t)i1 * 64 + c]);
        float v2 = bf2f(Xh[(size_t)i2 * 64 + c]);
        float v3 = bf2f(Xh[(size_t)i3 * 64 + c]);
        float v4 = bf2f(Xh[(size_t)i4 * 64 + c]);
        float v5 = bf2f(Xh[(size_t)i5 * 64 + c]);
        float v6 = bf2f(Xh[(size_t)i6 * 64 + c]);
        float v7 = bf2f(Xh[(size_t)i7 * 64 + c]);
        da += (double)v0; db += (double)v1;
        da += (double)v2; db += (double)v3;
        da += (double)v4; db += (double)v5;
        da += (double)v6; db += (double)v7;
    }
    for (; i < s1; ++i) da += (double)bf2f(Xh[(size_t)csr_src[i] * 64 + c]);
    float acc = (float)(da + db);
    float* p = out + (size_t)n * ldo + coff + c;
    *p = fmaxf(fmaf(acc, din_is[n], b[c]), 0.0f);
}

// ---- pull aggregation, f32 rows (tail): out[n,c] = sum + b[c] --------------
__global__ __launch_bounds__(256) void gather_f32_kernel(
    const int* __restrict__ row_start, const int* __restrict__ csr_src,
    const float* __restrict__ X, const float* __restrict__ b,
    float* __restrict__ out) {
    int n = blockIdx.x * 4 + (threadIdx.x >> 6);
    int c = threadIdx.x & 63;
    if (n >= NN) return;
    int s0 = row_start[n], s1 = row_start[n + 1];
    double da = 0.0, db = 0.0;
    int i = s0;
    int n8 = s0 + ((s1 - s0) & ~7);
    for (; i < n8; i += 8) {
        int i0 = csr_src[i + 0], i1 = csr_src[i + 1], i2 = csr_src[i + 2], i3 = csr_src[i + 3];
        int i4 = csr_src[i + 4], i5 = csr_src[i + 5], i6 = csr_src[i + 6], i7 = csr_src[i + 7];
        float v0 = X[(size_t)i0 * 64 + c];
        float v1 = X[(size_t)i1 * 64 + c];
        float v2 = X[(size_t)i2 * 64 + c];
        float v3 = X[(size_t)i3 * 64 + c];
        float v4 = X[(size_t)i4 * 64 + c];
        float v5 = X[(size_t)i5 * 64 + c];
        float v6 = X[(size_t)i6 * 64 + c];
        float v7 = X[(size_t)i7 * 64 + c];
        da += (double)v0; db += (double)v1;
        da += (double)v2; db += (double)v3;
        da += (double)v4; db += (double)v5;
        da += (double)v6; db += (double)v7;
    }
    for (; i < s1; ++i) da += (double)X[(size_t)csr_src[i] * 64 + c];
    out[(size_t)n * 64 + c] = (float)(da + db) + b[c];
}

extern "C" void kernel_launch(void* const* d_in, const int* in_sizes, int n_in,
                              void* d_out, int out_size, void* d_ws, size_t ws_size,
                              hipStream_t stream) {
    const float* feat  = (const float*)d_in[0];
    const int*   src   = (const int*)d_in[1];
    const int*   dst   = (const int*)d_in[2];
    const float* W[4]  = {(const float*)d_in[3], (const float*)d_in[5],
                          (const float*)d_in[7], (const float*)d_in[9]};
    const float* b[4]  = {(const float*)d_in[4], (const float*)d_in[6],
                          (const float*)d_in[8], (const float*)d_in[10]};
    const float* W_mlp = (const float*)d_in[11];
    const float* b_mlp = (const float*)d_in[12];
    float* out = (float*)d_out;

    // workspace layout:
    // C [NN*256 f]  (head transiently reused: dout_cnt [NN i] | cursor [NN i]
    //               | epos [NE i] — all dead before gather-0 writes C)
    // X [NN*64 f]   (bf16 view aliases the same region for layer gathers)
    // dout_is [NN f] | din_is [NN f] |
    // row_start [NN+1 i] | partials [256 i] | csr_src [NE i]
    float* C        = (float*)d_ws;
    int*   dout_cnt = (int*)d_ws;            // NN
    int*   cursor   = dout_cnt + NN;         // NN (doubles as din_cnt)
    int*   epos     = cursor + NN;           // NE
    float* X        = C + (size_t)NN * 256;
    unsigned short* Xh = (unsigned short*)X; // bf16 alias (used disjointly in time)
    float* dout_is  = X + (size_t)NN * 64;
    float* din_is   = dout_is + NN;
    int*   row_start = (int*)(din_is + NN);
    int*   partials  = row_start + NN + 1;
    int*   csr_src   = partials + 256;

    const int NBLK = (NN + 255) / 256;   // 196
    const int GBLK = (NN + 63) / 64;     // 782 (GEMM tiles)
    const int EBLK = (NE + 255) / 256;   // 3125

    // zero dout_cnt + cursor (contiguous)
    hipMemsetAsync(dout_cnt, 0, 2 * NN * sizeof(int), stream);

    // one atomic pass: out-degree counts + per-edge CSR slots (cursor = din)
    degree_cursor_kernel<<<EBLK, 256, 0, stream>>>(src, dst, dout_cnt, cursor, epos);

    // row_start = exscan(cursor); fill is atomic-free
    scan_local_kernel<<<NBLK, 256, 0, stream>>>(cursor, row_start, partials);
    scan_partials_kernel<<<1, 256, 0, stream>>>(partials, NBLK, row_start);
    scan_add_kernel<<<NBLK, 256, 0, stream>>>(row_start, partials);
    csr_fill_kernel<<<EBLK, 256, 0, stream>>>(src, dst, row_start, epos, csr_src);

    reduce_norm_kernel<<<NBLK, 256, 0, stream>>>(dout_cnt, cursor, dout_is, din_is);

    // layer 0 (K = 256 input feats) — bf16 X
    proj_kernel<256, true><<<GBLK, 256, 0, stream>>>(feat, 256, W[0], dout_is, Xh);
    gather_bf16_kernel<<<12500, 256, 0, stream>>>(row_start, csr_src, Xh, din_is, b[0], C, 256, 0);

    // layers 1..3 (K = 64), input = previous slice of C — bf16 X
    for (int i = 1; i < 4; ++i) {
        proj_kernel<64, true><<<GBLK, 256, 0, stream>>>(C + (i - 1) * 64, 256, W[i], dout_is, Xh);
        gather_bf16_kernel<<<12500, 256, 0, stream>>>(row_start, csr_src, Xh, din_is, b[i], C, 256, i * 64);
    }

    // tail: P = C @ W_mlp in f32 (project BEFORE the neighbor-sum; linear),
    // then out = b_mlp + segment_sum(P[src] -> dst)
    proj_kernel<256, false><<<GBLK, 256, 0, stream>>>(C, 256, W_mlp, nullptr, X);
    gather_f32_kernel<<<12500, 256, 0, stream>>>(row_start, csr_src, X, b_mlp, out);
}

// Round 7
// 431.964 us; speedup vs baseline: 1.1863x; 1.0806x over previous
//
#include <hip/hip_runtime.h>

#define NN 50000
#define NE 800000

// ---- bf16 helpers (manual RNE; values are finite) --------------------------
__device__ inline unsigned short f2bf(float f) {
    unsigned u = __float_as_uint(f);
    unsigned r = (u + 0x7FFFu + ((u >> 16) & 1u)) >> 16;
    return (unsigned short)r;
}
__device__ inline float bf2f(unsigned short h) {
    return __uint_as_float(((unsigned)h) << 16);
}

// ---- degree + CSR slot assignment in ONE atomic pass -----------------------
// dout_cnt[src]++ ; epos[e] = cursor[dst]++  (cursor doubles as din_cnt)
__global__ void degree_cursor_kernel(const int* __restrict__ src, const int* __restrict__ dst,
                                     int* __restrict__ dout_cnt, int* __restrict__ cursor,
                                     int* __restrict__ epos) {
    int e = blockIdx.x * 256 + threadIdx.x;
    if (e < NE) {
        atomicAdd(&dout_cnt[src[e]], 1);
        epos[e] = atomicAdd(&cursor[dst[e]], 1);
    }
}

// counts -> rsqrt normalizers (separate buffers, no aliasing)
__global__ void reduce_norm_kernel(const int* __restrict__ dout_cnt, const int* __restrict__ din_cnt,
                                   float* __restrict__ dout_is, float* __restrict__ din_is) {
    int n = blockIdx.x * 256 + threadIdx.x;
    if (n >= NN) return;
    dout_is[n] = rsqrtf(fmaxf((float)dout_cnt[n], 1.0f));
    din_is[n]  = rsqrtf(fmaxf((float)din_cnt[n], 1.0f));
}

// ---- scan helpers ----------------------------------------------------------
__device__ inline int wave_incl_scan(int v) {
    int lane = threadIdx.x & 63;
#pragma unroll
    for (int off = 1; off < 64; off <<= 1) {
        int t = __shfl_up(v, off, 64);
        if (lane >= off) v += t;
    }
    return v;
}

// A: per-block local exclusive scan of in-degree; block totals to partials
__global__ void scan_local_kernel(const int* __restrict__ din_cnt,
                                  int* __restrict__ row_start,
                                  int* __restrict__ partials) {
    __shared__ int wsum[4];
    int i = blockIdx.x * 256 + threadIdx.x;
    int v = (i < NN) ? din_cnt[i] : 0;
    int lane = threadIdx.x & 63, wid = threadIdx.x >> 6;
    int incl = wave_incl_scan(v);
    if (lane == 63) wsum[wid] = incl;
    __syncthreads();
    if (threadIdx.x == 0) {
        int s = 0;
        for (int w = 0; w < 4; ++w) { int t = wsum[w]; wsum[w] = s; s += t; }
        partials[blockIdx.x] = s;
    }
    __syncthreads();
    if (i < NN) row_start[i] = incl - v + wsum[wid];
}

// B: single-block exclusive scan of the 196 partials (in place)
__global__ void scan_partials_kernel(int* __restrict__ partials, int nparts,
                                     int* __restrict__ row_start) {
    __shared__ int wsum[4];
    int v = (threadIdx.x < nparts) ? partials[threadIdx.x] : 0;
    int lane = threadIdx.x & 63, wid = threadIdx.x >> 6;
    int incl = wave_incl_scan(v);
    if (lane == 63) wsum[wid] = incl;
    __syncthreads();
    if (threadIdx.x == 0) {
        int s = 0;
        for (int w = 0; w < 4; ++w) { int t = wsum[w]; wsum[w] = s; s += t; }
        row_start[NN] = NE;  // total in-degree == edge count
    }
    __syncthreads();
    if (threadIdx.x < nparts) partials[threadIdx.x] = incl - v + wsum[wid];
}

// C: add block offsets
__global__ void scan_add_kernel(int* __restrict__ row_start, const int* __restrict__ partials) {
    int i = blockIdx.x * 256 + threadIdx.x;
    if (i < NN) row_start[i] += partials[blockIdx.x];
}

// fill CSR: atomic-free scattered write using precomputed slots
__global__ void csr_fill_kernel(const int* __restrict__ src, const int* __restrict__ dst,
                                const int* __restrict__ row_start, const int* __restrict__ epos,
                                int* __restrict__ csr_src) {
    int e = blockIdx.x * 256 + threadIdx.x;
    if (e < NE) csr_src[row_start[dst[e]] + epos[e]] = src[e];
}

// ---- X = rowscale(A) @ W, register-blocked 64x64 tile ----------------------
// Block: 256 threads -> 64 rows x 64 cols, 4x4 acc per thread.
// A staged TRANSPOSED in LDS (pitch 68); W staged row-major. Staged row index
// CLAMPED to NN-1 (always-in-bounds loads); stores guarded.
// OUT_BF16: store X as bf16 (quarters gather instructions); else f32.
template <int K, bool OUT_BF16>
__global__ __launch_bounds__(256) void proj_kernel(
    const float* __restrict__ A, int lda,
    const float* __restrict__ W,   // K x 64, row-major
    const float* __restrict__ scale,
    void* __restrict__ Xout) {
    constexpr int KC = 64;
    constexpr int NCHUNK = K / KC;
    __shared__ float sAT[KC * 68];  // [k][row], pitch 68
    __shared__ float sW[KC * 64];   // [k][col]
    float acc[4][4] = {};

    const int t = threadIdx.x;
    const int tx = t & 15;          // col group: cols 4*tx..4*tx+3
    const int ty = t >> 4;          // row group: rows 4*ty..4*ty+3
    const int row0 = blockIdx.x * 64;

    const int srow = t & 63;        // staging: one row per lane
    const int f0 = t >> 6;          // staging float4-col base (0..3)
    int grow = row0 + srow;
    if (grow > NN - 1) grow = NN - 1;   // clamp: loads always in-bounds
    const float* arow = A + (size_t)grow * lda;

    for (int kc = 0; kc < NCHUNK; ++kc) {
#pragma unroll
        for (int it = 0; it < 4; ++it) {
            int k = (f0 + it * 4) * 4;
            float4 a4 = *reinterpret_cast<const float4*>(arow + kc * KC + k);
            sAT[(k + 0) * 68 + srow] = a4.x;
            sAT[(k + 1) * 68 + srow] = a4.y;
            sAT[(k + 2) * 68 + srow] = a4.z;
            sAT[(k + 3) * 68 + srow] = a4.w;
        }
        {
            const float4* wsrc = reinterpret_cast<const float4*>(W + (size_t)kc * KC * 64);
            float4* wdst = reinterpret_cast<float4*>(sW);
#pragma unroll
            for (int it = 0; it < 4; ++it) wdst[t + it * 256] = wsrc[t + it * 256];
        }
        __syncthreads();
#pragma unroll 8
        for (int k = 0; k < KC; ++k) {
            float4 av = *reinterpret_cast<const float4*>(&sAT[k * 68 + ty * 4]);
            float4 wv = *reinterpret_cast<const float4*>(&sW[k * 64 + tx * 4]);
            acc[0][0] = fmaf(av.x, wv.x, acc[0][0]);
            acc[0][1] = fmaf(av.x, wv.y, acc[0][1]);
            acc[0][2] = fmaf(av.x, wv.z, acc[0][2]);
            acc[0][3] = fmaf(av.x, wv.w, acc[0][3]);
            acc[1][0] = fmaf(av.y, wv.x, acc[1][0]);
            acc[1][1] = fmaf(av.y, wv.y, acc[1][1]);
            acc[1][2] = fmaf(av.y, wv.z, acc[1][2]);
            acc[1][3] = fmaf(av.y, wv.w, acc[1][3]);
            acc[2][0] = fmaf(av.z, wv.x, acc[2][0]);
            acc[2][1] = fmaf(av.z, wv.y, acc[2][1]);
            acc[2][2] = fmaf(av.z, wv.z, acc[2][2]);
            acc[2][3] = fmaf(av.z, wv.w, acc[2][3]);
            acc[3][0] = fmaf(av.w, wv.x, acc[3][0]);
            acc[3][1] = fmaf(av.w, wv.y, acc[3][1]);
            acc[3][2] = fmaf(av.w, wv.z, acc[3][2]);
            acc[3][3] = fmaf(av.w, wv.w, acc[3][3]);
        }
        __syncthreads();
    }
#pragma unroll
    for (int i = 0; i < 4; ++i) {
        int r = row0 + ty * 4 + i;
        if (r < NN) {
            float s = scale ? scale[r] : 1.0f;
            float4 o = {acc[i][0] * s, acc[i][1] * s, acc[i][2] * s, acc[i][3] * s};
            if (OUT_BF16) {
                ushort4 h = {f2bf(o.x), f2bf(o.y), f2bf(o.z), f2bf(o.w)};
                *reinterpret_cast<ushort4*>((unsigned short*)Xout + (size_t)r * 64 + tx * 4) = h;
            } else {
                *reinterpret_cast<float4*>((float*)Xout + (size_t)r * 64 + tx * 4) = o;
            }
        }
    }
}

// ---- pull aggregation, 4 neighbor rows per load instruction ----------------
// One wave per dst row. lane = group g (lane>>4) x col-quad c4 ((lane&15)*4).
// Each ushort4 load covers one full 128B bf16 row across 16 lanes; the 4
// groups fetch 4 DIFFERENT neighbors per instruction. f64 group-partials
// (order-insensitive vs atomic-assigned CSR slot order) are combined with
// two shfl_xor rounds; group 0 stores float4.
// relu!=0: out = relu(sum*din_is[n] + b[c]);  relu==0: out = sum + b[c].
__global__ __launch_bounds__(256) void gather4_bf16_kernel(
    const int* __restrict__ row_start, const int* __restrict__ csr_src,
    const unsigned short* __restrict__ Xh, const float* __restrict__ din_is,
    const float* __restrict__ b, float* __restrict__ out,
    int ldo, int coff, int relu) {
    int n = blockIdx.x * 4 + (threadIdx.x >> 6);
    if (n >= NN) return;
    int lane = threadIdx.x & 63;
    int g = lane >> 4;              // neighbor group 0..3
    int c4 = (lane & 15) << 2;      // cols c4..c4+3
    int s0 = row_start[n], s1 = row_start[n + 1];
    double a0 = 0.0, a1 = 0.0, a2 = 0.0, a3 = 0.0;
    int i = s0;
    // main: 8 neighbors per iter (2 per group, 2 row-load instrs in flight)
    for (; i + 8 <= s1; i += 8) {
        int ia = csr_src[i + g];
        int ib = csr_src[i + 4 + g];
        ushort4 va = *reinterpret_cast<const ushort4*>(Xh + (size_t)ia * 64 + c4);
        ushort4 vb = *reinterpret_cast<const ushort4*>(Xh + (size_t)ib * 64 + c4);
        a0 += (double)bf2f(va.x); a1 += (double)bf2f(va.y);
        a2 += (double)bf2f(va.z); a3 += (double)bf2f(va.w);
        a0 += (double)bf2f(vb.x); a1 += (double)bf2f(vb.y);
        a2 += (double)bf2f(vb.z); a3 += (double)bf2f(vb.w);
    }
    // tail: up to 7 neighbors, group-guarded
    for (; i < s1; i += 4) {
        if (i + g < s1) {
            int ia = csr_src[i + g];
            ushort4 va = *reinterpret_cast<const ushort4*>(Xh + (size_t)ia * 64 + c4);
            a0 += (double)bf2f(va.x); a1 += (double)bf2f(va.y);
            a2 += (double)bf2f(va.z); a3 += (double)bf2f(va.w);
        }
    }
    // combine the 4 groups (lanes l, l^16, l^32, l^48 share the same c4)
    a0 += __shfl_xor(a0, 16, 64); a0 += __shfl_xor(a0, 32, 64);
    a1 += __shfl_xor(a1, 16, 64); a1 += __shfl_xor(a1, 32, 64);
    a2 += __shfl_xor(a2, 16, 64); a2 += __shfl_xor(a2, 32, 64);
    a3 += __shfl_xor(a3, 16, 64); a3 += __shfl_xor(a3, 32, 64);
    if (g == 0) {
        float4 o;
        if (relu) {
            float di = din_is[n];
            o.x = fmaxf(fmaf((float)a0, di, b[c4 + 0]), 0.0f);
            o.y = fmaxf(fmaf((float)a1, di, b[c4 + 1]), 0.0f);
            o.z = fmaxf(fmaf((float)a2, di, b[c4 + 2]), 0.0f);
            o.w = fmaxf(fmaf((float)a3, di, b[c4 + 3]), 0.0f);
        } else {
            o.x = (float)a0 + b[c4 + 0];
            o.y = (float)a1 + b[c4 + 1];
            o.z = (float)a2 + b[c4 + 2];
            o.w = (float)a3 + b[c4 + 3];
        }
        *reinterpret_cast<float4*>(out + (size_t)n * ldo + coff + c4) = o;
    }
}

extern "C" void kernel_launch(void* const* d_in, const int* in_sizes, int n_in,
                              void* d_out, int out_size, void* d_ws, size_t ws_size,
                              hipStream_t stream) {
    const float* feat  = (const float*)d_in[0];
    const int*   src   = (const int*)d_in[1];
    const int*   dst   = (const int*)d_in[2];
    const float* W[4]  = {(const float*)d_in[3], (const float*)d_in[5],
                          (const float*)d_in[7], (const float*)d_in[9]};
    const float* b[4]  = {(const float*)d_in[4], (const float*)d_in[6],
                          (const float*)d_in[8], (const float*)d_in[10]};
    const float* W_mlp = (const float*)d_in[11];
    const float* b_mlp = (const float*)d_in[12];
    float* out = (float*)d_out;

    // workspace layout:
    // C [NN*256 f]  (head transiently reused: dout_cnt [NN i] | cursor [NN i]
    //               | epos [NE i] — all dead before gather-0 writes C)
    // X [NN*64 f]   (bf16 view aliases the same region)
    // dout_is [NN f] | din_is [NN f] |
    // row_start [NN+1 i] | partials [256 i] | csr_src [NE i]
    float* C        = (float*)d_ws;
    int*   dout_cnt = (int*)d_ws;            // NN
    int*   cursor   = dout_cnt + NN;         // NN (doubles as din_cnt)
    int*   epos     = cursor + NN;           // NE
    float* X        = C + (size_t)NN * 256;
    unsigned short* Xh = (unsigned short*)X; // bf16 alias (used disjointly in time)
    float* dout_is  = X + (size_t)NN * 64;
    float* din_is   = dout_is + NN;
    int*   row_start = (int*)(din_is + NN);
    int*   partials  = row_start + NN + 1;
    int*   csr_src   = partials + 256;

    const int NBLK = (NN + 255) / 256;   // 196
    const int GBLK = (NN + 63) / 64;     // 782 (GEMM tiles)
    const int EBLK = (NE + 255) / 256;   // 3125

    // zero dout_cnt + cursor (contiguous)
    hipMemsetAsync(dout_cnt, 0, 2 * NN * sizeof(int), stream);

    // one atomic pass: out-degree counts + per-edge CSR slots (cursor = din)
    degree_cursor_kernel<<<EBLK, 256, 0, stream>>>(src, dst, dout_cnt, cursor, epos);

    // row_start = exscan(cursor); fill is atomic-free
    scan_local_kernel<<<NBLK, 256, 0, stream>>>(cursor, row_start, partials);
    scan_partials_kernel<<<1, 256, 0, stream>>>(partials, NBLK, row_start);
    scan_add_kernel<<<NBLK, 256, 0, stream>>>(row_start, partials);
    csr_fill_kernel<<<EBLK, 256, 0, stream>>>(src, dst, row_start, epos, csr_src);

    reduce_norm_kernel<<<NBLK, 256, 0, stream>>>(dout_cnt, cursor, dout_is, din_is);

    // layer 0 (K = 256 input feats) — bf16 X
    proj_kernel<256, true><<<GBLK, 256, 0, stream>>>(feat, 256, W[0], dout_is, Xh);
    gather4_bf16_kernel<<<12500, 256, 0, stream>>>(row_start, csr_src, Xh, din_is, b[0], C, 256, 0, 1);

    // layers 1..3 (K = 64), input = previous slice of C — bf16 X
    for (int i = 1; i < 4; ++i) {
        proj_kernel<64, true><<<GBLK, 256, 0, stream>>>(C + (i - 1) * 64, 256, W[i], dout_is, Xh);
        gather4_bf16_kernel<<<12500, 256, 0, stream>>>(row_start, csr_src, Xh, din_is, b[i], C, 256, i * 64, 1);
    }

    // tail: P = C @ W_mlp as bf16 (project BEFORE the neighbor-sum; linear),
    // then out = b_mlp + segment_sum(P[src] -> dst)
    proj_kernel<256, true><<<GBLK, 256, 0, stream>>>(C, 256, W_mlp, nullptr, Xh);
    gather4_bf16_kernel<<<12500, 256, 0, stream>>>(row_start, csr_src, Xh, nullptr, b_mlp, out, 64, 0, 0);
}

// Round 8
// 415.702 us; speedup vs baseline: 1.2327x; 1.0391x over previous
//
#include <hip/hip_runtime.h>

#define NN 50000
#define NE 800000

// ---- bf16 helpers (manual RNE; values are finite) --------------------------
__device__ inline unsigned short f2bf(float f) {
    unsigned u = __float_as_uint(f);
    unsigned r = (u + 0x7FFFu + ((u >> 16) & 1u)) >> 16;
    return (unsigned short)r;
}
__device__ inline float bf2f(unsigned short h) {
    return __uint_as_float(((unsigned)h) << 16);
}

// ---- degree + CSR slot assignment, 2 edges/thread --------------------------
// dout_cnt[src]++ ; epos[e] = cursor[dst]++  (cursor doubles as din_cnt)
__global__ void degree_cursor_kernel(const int* __restrict__ src, const int* __restrict__ dst,
                                     int* __restrict__ dout_cnt, int* __restrict__ cursor,
                                     int* __restrict__ epos) {
    const int H = NE / 2;
    int e = blockIdx.x * 256 + threadIdx.x;
    if (e < H) {
        int sa = src[e], da = dst[e];
        int sb = src[e + H], db = dst[e + H];
        atomicAdd(&dout_cnt[sa], 1);
        atomicAdd(&dout_cnt[sb], 1);
        int pa = atomicAdd(&cursor[da], 1);
        int pb = atomicAdd(&cursor[db], 1);
        epos[e] = pa;
        epos[e + H] = pb;
    }
}

// ---- scan helpers ----------------------------------------------------------
__device__ inline int wave_incl_scan(int v) {
    int lane = threadIdx.x & 63;
#pragma unroll
    for (int off = 1; off < 64; off <<= 1) {
        int t = __shfl_up(v, off, 64);
        if (lane >= off) v += t;
    }
    return v;
}

// A: per-block local exclusive scan of in-degree; block totals to partials
__global__ void scan_local_kernel(const int* __restrict__ din_cnt,
                                  int* __restrict__ row_start,
                                  int* __restrict__ partials) {
    __shared__ int wsum[4];
    int i = blockIdx.x * 256 + threadIdx.x;
    int v = (i < NN) ? din_cnt[i] : 0;
    int lane = threadIdx.x & 63, wid = threadIdx.x >> 6;
    int incl = wave_incl_scan(v);
    if (lane == 63) wsum[wid] = incl;
    __syncthreads();
    if (threadIdx.x == 0) {
        int s = 0;
        for (int w = 0; w < 4; ++w) { int t = wsum[w]; wsum[w] = s; s += t; }
        partials[blockIdx.x] = s;
    }
    __syncthreads();
    if (i < NN) row_start[i] = incl - v + wsum[wid];
}

// B: single-block exclusive scan of the 196 partials (in place)
__global__ void scan_partials_kernel(int* __restrict__ partials, int nparts,
                                     int* __restrict__ row_start) {
    __shared__ int wsum[4];
    int v = (threadIdx.x < nparts) ? partials[threadIdx.x] : 0;
    int lane = threadIdx.x & 63, wid = threadIdx.x >> 6;
    int incl = wave_incl_scan(v);
    if (lane == 63) wsum[wid] = incl;
    __syncthreads();
    if (threadIdx.x == 0) {
        int s = 0;
        for (int w = 0; w < 4; ++w) { int t = wsum[w]; wsum[w] = s; s += t; }
        row_start[NN] = NE;  // total in-degree == edge count
    }
    __syncthreads();
    if (threadIdx.x < nparts) partials[threadIdx.x] = incl - v + wsum[wid];
}

// C: add block offsets + emit rsqrt normalizers (fused, one pass over nodes)
__global__ void scan_add_norm_kernel(int* __restrict__ row_start, const int* __restrict__ partials,
                                     const int* __restrict__ dout_cnt, const int* __restrict__ din_cnt,
                                     float* __restrict__ dout_is, float* __restrict__ din_is) {
    int i = blockIdx.x * 256 + threadIdx.x;
    if (i < NN) {
        row_start[i] += partials[blockIdx.x];
        dout_is[i] = rsqrtf(fmaxf((float)dout_cnt[i], 1.0f));
        din_is[i]  = rsqrtf(fmaxf((float)din_cnt[i], 1.0f));
    }
}

// fill CSR: atomic-free scattered write using precomputed slots
__global__ void csr_fill_kernel(const int* __restrict__ src, const int* __restrict__ dst,
                                const int* __restrict__ row_start, const int* __restrict__ epos,
                                int* __restrict__ csr_src) {
    int e = blockIdx.x * 256 + threadIdx.x;
    if (e < NE) csr_src[row_start[dst[e]] + epos[e]] = src[e];
}

// ---- X = rowscale(A) @ W, register-blocked 64x64 tile ----------------------
// Block: 256 threads -> 64 rows x 64 cols, 4x4 acc per thread.
// A staged TRANSPOSED in LDS (pitch 68); W staged row-major. Staged row index
// CLAMPED to NN-1 (always-in-bounds loads); stores guarded.
// OUT_BF16: store X as bf16 (quarters gather instructions); else f32.
template <int K, bool OUT_BF16>
__global__ __launch_bounds__(256) void proj_kernel(
    const float* __restrict__ A, int lda,
    const float* __restrict__ W,   // K x 64, row-major
    const float* __restrict__ scale,
    void* __restrict__ Xout) {
    constexpr int KC = 64;
    constexpr int NCHUNK = K / KC;
    __shared__ float sAT[KC * 68];  // [k][row], pitch 68
    __shared__ float sW[KC * 64];   // [k][col]
    float acc[4][4] = {};

    const int t = threadIdx.x;
    const int tx = t & 15;          // col group: cols 4*tx..4*tx+3
    const int ty = t >> 4;          // row group: rows 4*ty..4*ty+3
    const int row0 = blockIdx.x * 64;

    const int srow = t & 63;        // staging: one row per lane
    const int f0 = t >> 6;          // staging float4-col base (0..3)
    int grow = row0 + srow;
    if (grow > NN - 1) grow = NN - 1;   // clamp: loads always in-bounds
    const float* arow = A + (size_t)grow * lda;

    for (int kc = 0; kc < NCHUNK; ++kc) {
#pragma unroll
        for (int it = 0; it < 4; ++it) {
            int k = (f0 + it * 4) * 4;
            float4 a4 = *reinterpret_cast<const float4*>(arow + kc * KC + k);
            sAT[(k + 0) * 68 + srow] = a4.x;
            sAT[(k + 1) * 68 + srow] = a4.y;
            sAT[(k + 2) * 68 + srow] = a4.z;
            sAT[(k + 3) * 68 + srow] = a4.w;
        }
        {
            const float4* wsrc = reinterpret_cast<const float4*>(W + (size_t)kc * KC * 64);
            float4* wdst = reinterpret_cast<float4*>(sW);
#pragma unroll
            for (int it = 0; it < 4; ++it) wdst[t + it * 256] = wsrc[t + it * 256];
        }
        __syncthreads();
#pragma unroll 8
        for (int k = 0; k < KC; ++k) {
            float4 av = *reinterpret_cast<const float4*>(&sAT[k * 68 + ty * 4]);
            float4 wv = *reinterpret_cast<const float4*>(&sW[k * 64 + tx * 4]);
            acc[0][0] = fmaf(av.x, wv.x, acc[0][0]);
            acc[0][1] = fmaf(av.x, wv.y, acc[0][1]);
            acc[0][2] = fmaf(av.x, wv.z, acc[0][2]);
            acc[0][3] = fmaf(av.x, wv.w, acc[0][3]);
            acc[1][0] = fmaf(av.y, wv.x, acc[1][0]);
            acc[1][1] = fmaf(av.y, wv.y, acc[1][1]);
            acc[1][2] = fmaf(av.y, wv.z, acc[1][2]);
            acc[1][3] = fmaf(av.y, wv.w, acc[1][3]);
            acc[2][0] = fmaf(av.z, wv.x, acc[2][0]);
            acc[2][1] = fmaf(av.z, wv.y, acc[2][1]);
            acc[2][2] = fmaf(av.z, wv.z, acc[2][2]);
            acc[2][3] = fmaf(av.z, wv.w, acc[2][3]);
            acc[3][0] = fmaf(av.w, wv.x, acc[3][0]);
            acc[3][1] = fmaf(av.w, wv.y, acc[3][1]);
            acc[3][2] = fmaf(av.w, wv.z, acc[3][2]);
            acc[3][3] = fmaf(av.w, wv.w, acc[3][3]);
        }
        __syncthreads();
    }
#pragma unroll
    for (int i = 0; i < 4; ++i) {
        int r = row0 + ty * 4 + i;
        if (r < NN) {
            float s = scale ? scale[r] : 1.0f;
            float4 o = {acc[i][0] * s, acc[i][1] * s, acc[i][2] * s, acc[i][3] * s};
            if (OUT_BF16) {
                ushort4 h = {f2bf(o.x), f2bf(o.y), f2bf(o.z), f2bf(o.w)};
                *reinterpret_cast<ushort4*>((unsigned short*)Xout + (size_t)r * 64 + tx * 4) = h;
            } else {
                *reinterpret_cast<float4*>((float*)Xout + (size_t)r * 64 + tx * 4) = o;
            }
        }
    }
}

// ---- pull aggregation, up to 4 row-loads in flight per wave ----------------
// One wave per dst row. lane = group g (lane>>4) x col-quad c4 ((lane&15)*4).
// Each ushort4 load covers one full 128B bf16 row across 16 lanes; groups
// fetch different neighbors. Unroll ladder 16/8/4/guard maximizes outstanding
// misses (deg~16 -> most rows take one 16-wide iteration = 4 loads in flight).
// f64 group-partials (order-insensitive vs atomic-assigned CSR slot order),
// combined with two shfl_xor rounds; group 0 stores float4.
// relu!=0: out = relu(sum*din_is[n] + b[c]);  relu==0: out = sum + b[c].
__global__ __launch_bounds__(256) void gather4_bf16_kernel(
    const int* __restrict__ row_start, const int* __restrict__ csr_src,
    const unsigned short* __restrict__ Xh, const float* __restrict__ din_is,
    const float* __restrict__ b, float* __restrict__ out,
    int ldo, int coff, int relu) {
    int n = blockIdx.x * 4 + (threadIdx.x >> 6);
    if (n >= NN) return;
    int lane = threadIdx.x & 63;
    int g = lane >> 4;              // neighbor group 0..3
    int c4 = (lane & 15) << 2;      // cols c4..c4+3
    int s0 = row_start[n], s1 = row_start[n + 1];
    double a0 = 0.0, a1 = 0.0, a2 = 0.0, a3 = 0.0;
    int i = s0;
    // 16 neighbors/iter: 4 independent row loads in flight
    for (; i + 16 <= s1; i += 16) {
        int ia = csr_src[i + g];
        int ib = csr_src[i + 4 + g];
        int ic = csr_src[i + 8 + g];
        int id = csr_src[i + 12 + g];
        ushort4 va = *reinterpret_cast<const ushort4*>(Xh + (size_t)ia * 64 + c4);
        ushort4 vb = *reinterpret_cast<const ushort4*>(Xh + (size_t)ib * 64 + c4);
        ushort4 vc = *reinterpret_cast<const ushort4*>(Xh + (size_t)ic * 64 + c4);
        ushort4 vd = *reinterpret_cast<const ushort4*>(Xh + (size_t)id * 64 + c4);
        a0 += (double)bf2f(va.x); a1 += (double)bf2f(va.y);
        a2 += (double)bf2f(va.z); a3 += (double)bf2f(va.w);
        a0 += (double)bf2f(vb.x); a1 += (double)bf2f(vb.y);
        a2 += (double)bf2f(vb.z); a3 += (double)bf2f(vb.w);
        a0 += (double)bf2f(vc.x); a1 += (double)bf2f(vc.y);
        a2 += (double)bf2f(vc.z); a3 += (double)bf2f(vc.w);
        a0 += (double)bf2f(vd.x); a1 += (double)bf2f(vd.y);
        a2 += (double)bf2f(vd.z); a3 += (double)bf2f(vd.w);
    }
    // 8 neighbors/iter: 2 loads in flight
    for (; i + 8 <= s1; i += 8) {
        int ia = csr_src[i + g];
        int ib = csr_src[i + 4 + g];
        ushort4 va = *reinterpret_cast<const ushort4*>(Xh + (size_t)ia * 64 + c4);
        ushort4 vb = *reinterpret_cast<const ushort4*>(Xh + (size_t)ib * 64 + c4);
        a0 += (double)bf2f(va.x); a1 += (double)bf2f(va.y);
        a2 += (double)bf2f(va.z); a3 += (double)bf2f(va.w);
        a0 += (double)bf2f(vb.x); a1 += (double)bf2f(vb.y);
        a2 += (double)bf2f(vb.z); a3 += (double)bf2f(vb.w);
    }
    // 4 neighbors
    for (; i + 4 <= s1; i += 4) {
        int ia = csr_src[i + g];
        ushort4 va = *reinterpret_cast<const ushort4*>(Xh + (size_t)ia * 64 + c4);
        a0 += (double)bf2f(va.x); a1 += (double)bf2f(va.y);
        a2 += (double)bf2f(va.z); a3 += (double)bf2f(va.w);
    }
    // <4 remaining, group-guarded
    if (i + g < s1) {
        int ia = csr_src[i + g];
        ushort4 va = *reinterpret_cast<const ushort4*>(Xh + (size_t)ia * 64 + c4);
        a0 += (double)bf2f(va.x); a1 += (double)bf2f(va.y);
        a2 += (double)bf2f(va.z); a3 += (double)bf2f(va.w);
    }
    // combine the 4 groups (lanes l, l^16, l^32, l^48 share the same c4)
    a0 += __shfl_xor(a0, 16, 64); a0 += __shfl_xor(a0, 32, 64);
    a1 += __shfl_xor(a1, 16, 64); a1 += __shfl_xor(a1, 32, 64);
    a2 += __shfl_xor(a2, 16, 64); a2 += __shfl_xor(a2, 32, 64);
    a3 += __shfl_xor(a3, 16, 64); a3 += __shfl_xor(a3, 32, 64);
    if (g == 0) {
        float4 o;
        if (relu) {
            float di = din_is[n];
            o.x = fmaxf(fmaf((float)a0, di, b[c4 + 0]), 0.0f);
            o.y = fmaxf(fmaf((float)a1, di, b[c4 + 1]), 0.0f);
            o.z = fmaxf(fmaf((float)a2, di, b[c4 + 2]), 0.0f);
            o.w = fmaxf(fmaf((float)a3, di, b[c4 + 3]), 0.0f);
        } else {
            o.x = (float)a0 + b[c4 + 0];
            o.y = (float)a1 + b[c4 + 1];
            o.z = (float)a2 + b[c4 + 2];
            o.w = (float)a3 + b[c4 + 3];
        }
        *reinterpret_cast<float4*>(out + (size_t)n * ldo + coff + c4) = o;
    }
}

extern "C" void kernel_launch(void* const* d_in, const int* in_sizes, int n_in,
                              void* d_out, int out_size, void* d_ws, size_t ws_size,
                              hipStream_t stream) {
    const float* feat  = (const float*)d_in[0];
    const int*   src   = (const int*)d_in[1];
    const int*   dst   = (const int*)d_in[2];
    const float* W[4]  = {(const float*)d_in[3], (const float*)d_in[5],
                          (const float*)d_in[7], (const float*)d_in[9]};
    const float* b[4]  = {(const float*)d_in[4], (const float*)d_in[6],
                          (const float*)d_in[8], (const float*)d_in[10]};
    const float* W_mlp = (const float*)d_in[11];
    const float* b_mlp = (const float*)d_in[12];
    float* out = (float*)d_out;

    // workspace layout:
    // C [NN*256 f]  (head transiently reused: dout_cnt [NN i] | cursor [NN i]
    //               | epos [NE i] — all dead before gather-0 writes C)
    // X [NN*64 f]   (bf16 view aliases the same region)
    // dout_is [NN f] | din_is [NN f] |
    // row_start [NN+1 i] | partials [256 i] | csr_src [NE i]
    float* C        = (float*)d_ws;
    int*   dout_cnt = (int*)d_ws;            // NN
    int*   cursor   = dout_cnt + NN;         // NN (doubles as din_cnt)
    int*   epos     = cursor + NN;           // NE
    float* X        = C + (size_t)NN * 256;
    unsigned short* Xh = (unsigned short*)X; // bf16 alias (used disjointly in time)
    float* dout_is  = X + (size_t)NN * 64;
    float* din_is   = dout_is + NN;
    int*   row_start = (int*)(din_is + NN);
    int*   partials  = row_start + NN + 1;
    int*   csr_src   = partials + 256;

    const int NBLK = (NN + 255) / 256;   // 196
    const int GBLK = (NN + 63) / 64;     // 782 (GEMM tiles)
    const int EBLK = (NE + 255) / 256;   // 3125
    const int HBLK = (NE / 2 + 255) / 256;  // 1563

    // zero dout_cnt + cursor (contiguous)
    hipMemsetAsync(dout_cnt, 0, 2 * NN * sizeof(int), stream);

    // one atomic pass: out-degree counts + per-edge CSR slots (cursor = din)
    degree_cursor_kernel<<<HBLK, 256, 0, stream>>>(src, dst, dout_cnt, cursor, epos);

    // row_start = exscan(cursor); fill is atomic-free
    scan_local_kernel<<<NBLK, 256, 0, stream>>>(cursor, row_start, partials);
    scan_partials_kernel<<<1, 256, 0, stream>>>(partials, NBLK, row_start);
    scan_add_norm_kernel<<<NBLK, 256, 0, stream>>>(row_start, partials, dout_cnt, cursor,
                                                   dout_is, din_is);
    csr_fill_kernel<<<EBLK, 256, 0, stream>>>(src, dst, row_start, epos, csr_src);

    // layer 0 (K = 256 input feats) — bf16 X
    proj_kernel<256, true><<<GBLK, 256, 0, stream>>>(feat, 256, W[0], dout_is, Xh);
    gather4_bf16_kernel<<<12500, 256, 0, stream>>>(row_start, csr_src, Xh, din_is, b[0], C, 256, 0, 1);

    // layers 1..3 (K = 64), input = previous slice of C — bf16 X
    for (int i = 1; i < 4; ++i) {
        proj_kernel<64, true><<<GBLK, 256, 0, stream>>>(C + (i - 1) * 64, 256, W[i], dout_is, Xh);
        gather4_bf16_kernel<<<12500, 256, 0, stream>>>(row_start, csr_src, Xh, din_is, b[i], C, 256, i * 64, 1);
    }

    // tail: P = C @ W_mlp as bf16 (project BEFORE the neighbor-sum; linear),
    // then out = b_mlp + segment_sum(P[src] -> dst)
    proj_kernel<256, true><<<GBLK, 256, 0, stream>>>(C, 256, W_mlp, nullptr, Xh);
    gather4_bf16_kernel<<<12500, 256, 0, stream>>>(row_start, csr_src, Xh, nullptr, b_mlp, out, 64, 0, 0);
}